// Round 2
// baseline (585.769 us; speedup 1.0000x reference)
//
#include <hip/hip_runtime.h>

// SpecCnn1d: y[b,o,f] = relu( sum_k x[b,o+k] * w[f,k] ), stride 1
// B=64, L=16384, F=128, K=16, out_len=16369.
// Output 536 MB fp32 -> HBM write-bound, roofline ~85-95 us.
//
// v2: float4 stores (thread owns 4 consecutive filters), 8 consecutive o per
// thread sharing one 24-float x window loaded as 6 float4.
//   block = 256 threads = 32 f-lanes (4 filters each) x 8 o-groups (8 o each)
//   block tile = all 128 filters x 64 o positions, one batch row.

constexpr int K_TAPS = 16;
constexpr int F_FILT = 128;
constexpr int O_PER_THREAD = 8;
constexpr int O_TILE = 64;

__global__ __launch_bounds__(256, 4) void SpecCnn1d_conv_kernel(
    const float* __restrict__ x,     // [B, L]
    const float* __restrict__ w,     // [F, K]
    float* __restrict__ y,           // [B, out_len, F]
    int L, int out_len)
{
    const int tid    = threadIdx.x;
    const int fg     = (tid & 31) * 4;                  // filter base: 0,4,...,124
    const int og     = tid >> 5;                        // o-group 0..7
    const int b      = blockIdx.y;
    const int o_base = blockIdx.x * O_TILE + og * O_PER_THREAD;  // multiple of 8

    // ---- weights: 4 filters x 16 taps -> 64 VGPRs (L2-cached, 8 KB total) ----
    float wr[4][K_TAPS];
    #pragma unroll
    for (int ff = 0; ff < 4; ++ff) {
        const float4* w4 = reinterpret_cast<const float4*>(w + (fg + ff) * K_TAPS);
        #pragma unroll
        for (int i = 0; i < K_TAPS / 4; ++i) {
            float4 v = w4[i];
            wr[ff][4*i+0] = v.x; wr[ff][4*i+1] = v.y;
            wr[ff][4*i+2] = v.z; wr[ff][4*i+3] = v.w;
        }
    }

    // ---- x window: 24 floats cover o_base .. o_base+7+15 ----
    const float* xb = x + (size_t)b * L;
    float xs[O_PER_THREAD + K_TAPS];                    // 24
    if (o_base + 23 < L) {
        // fast path: 6 aligned float4 loads (o_base % 8 == 0)
        const float4* x4 = reinterpret_cast<const float4*>(xb + o_base);
        #pragma unroll
        for (int i = 0; i < 6; ++i) {
            float4 v = x4[i];
            xs[4*i+0] = v.x; xs[4*i+1] = v.y; xs[4*i+2] = v.z; xs[4*i+3] = v.w;
        }
    } else {
        // tail blocks only: scalar clamped loads (clamped values feed only
        // o >= out_len which are never stored)
        #pragma unroll
        for (int j = 0; j < 24; ++j) {
            int xi = o_base + j;
            xs[j] = xb[(xi < L) ? xi : (L - 1)];
        }
    }

    float* yb = y + (size_t)b * out_len * F_FILT + fg;

    #pragma unroll
    for (int i = 0; i < O_PER_THREAD; ++i) {
        float a0 = 0.f, a1 = 0.f, a2 = 0.f, a3 = 0.f;   // 4 independent chains
        #pragma unroll
        for (int k = 0; k < K_TAPS; ++k) {
            const float xv = xs[i + k];
            a0 = fmaf(xv, wr[0][k], a0);
            a1 = fmaf(xv, wr[1][k], a1);
            a2 = fmaf(xv, wr[2][k], a2);
            a3 = fmaf(xv, wr[3][k], a3);
        }
        const int o = o_base + i;
        if (o < out_len) {
            float4 r;
            r.x = fmaxf(a0, 0.f); r.y = fmaxf(a1, 0.f);
            r.z = fmaxf(a2, 0.f); r.w = fmaxf(a3, 0.f);
            *reinterpret_cast<float4*>(yb + (size_t)o * F_FILT) = r;
        }
    }
}

extern "C" void kernel_launch(void* const* d_in, const int* in_sizes, int n_in,
                              void* d_out, int out_size, void* d_ws, size_t ws_size,
                              hipStream_t stream) {
    const float* x = (const float*)d_in[0];   // 64*16384 fp32
    const float* w = (const float*)d_in[1];   // 128*16  fp32
    float*       y = (float*)d_out;           // 64*16369*128 fp32

    const int B = 64;
    const int L = in_sizes[0] / B;            // 16384
    const int out_len = L - K_TAPS + 1;       // 16369

    dim3 grid((out_len + O_TILE - 1) / O_TILE, B);   // (256, 64)
    dim3 block(256);
    SpecCnn1d_conv_kernel<<<grid, block, 0, stream>>>(x, w, y, L, out_len);
}